// Round 12
// baseline (329.615 us; speedup 1.0000x reference)
//
#include <hip/hip_runtime.h>
#include <math.h>

typedef __attribute__((ext_vector_type(8))) __bf16 bf16x8;
typedef __attribute__((ext_vector_type(4))) __bf16 bf16x4;
typedef __attribute__((ext_vector_type(4))) float f32x4;

__device__ __forceinline__ float elu_f(float v) {
    return v > 0.f ? v : (expf(v) - 1.f);
}

// ---------------------------------------------------------------------------
// Merged prep: conv-weight reorder (blocks 0..831) + GIN transpose/hi-lo
// split (blocks 832..888).
// ---------------------------------------------------------------------------
__global__ __launch_bounds__(256) void prep_all(
    const float* __restrict__ w1, const float* __restrict__ w2,
    const float* __restrict__ w3, const float* __restrict__ w4,
    __bf16* __restrict__ t1, __bf16* __restrict__ t2,
    __bf16* __restrict__ t3, __bf16* __restrict__ t4,
    const float* __restrict__ g0w1, const float* __restrict__ g0w2,
    const float* __restrict__ g1w1, const float* __restrict__ g1w2,
    const float* __restrict__ g2w1, const float* __restrict__ g2w2,
    __bf16* __restrict__ d0, __bf16* __restrict__ d1, __bf16* __restrict__ d2,
    __bf16* __restrict__ d3, __bf16* __restrict__ d4, __bf16* __restrict__ d5)
{
    __shared__ float tl[64][68];
    const int bigbid = blockIdx.x;
    if (bigbid < 832) {
        int idx = bigbid * 256 + threadIdx.x;
        if (idx < 81920) {
            int k = idx / 4096, r = idx - k * 4096, co = r >> 6, ci = r & 63;
            t1[idx] = (__bf16)w1[(co * 64 + ci) * 20 + k];
        } else if (idx < 163840) {
            int j = idx - 81920;
            int k = j / 4096, r = j - k * 4096, co = r >> 6, ci = r & 63;
            t2[j] = (__bf16)w2[(co * 64 + ci) * 20 + k];
        } else if (idx < 188416) {
            int j = idx - 163840;
            int k = j / 4096, r = j - k * 4096, co = r >> 6, ci = r & 63;
            t3[j] = (__bf16)w3[(co * 64 + ci) * 6 + k];
        } else if (idx < 212992) {
            int j = idx - 188416;
            int k = j / 4096, r = j - k * 4096, co = r >> 6, ci = r & 63;
            t4[j] = (__bf16)w4[(co * 64 + ci) * 6 + k];
        }
        return;
    }
    int bid = bigbid - 832;
    const float* src; __bf16* dst; int K, O, Kpad, Opad, tile;
    if (bid < 4)       { src = g0w1; dst = d0; K = 35;   O = 256; Kpad = 64;   Opad = 256; tile = bid; }
    else if (bid < 20) { src = g0w2; dst = d1; K = 256;  O = 256; Kpad = 256;  Opad = 256; tile = bid - 4; }
    else if (bid < 36) { src = g1w1; dst = d2; K = 256;  O = 256; Kpad = 256;  Opad = 256; tile = bid - 20; }
    else if (bid < 52) { src = g1w2; dst = d3; K = 256;  O = 256; Kpad = 256;  Opad = 256; tile = bid - 36; }
    else if (bid < 56) { src = g2w1; dst = d4; K = 256;  O = 35;  Kpad = 256;  Opad = 64;  tile = bid - 52; }
    else               { src = g2w2; dst = d5; K = 35;   O = 35;  Kpad = 64;   Opad = 64;  tile = 0; }
    int ktiles = Kpad >> 6;
    int ot = tile / ktiles, kt = tile - ot * ktiles;
    int k0 = kt * 64, o0 = ot * 64;
    size_t LOFF = (size_t)Opad * Kpad;
    int c = threadIdx.x & 63, rr = threadIdx.x >> 6;
    #pragma unroll
    for (int it = 0; it < 16; ++it) {
        int r = rr + it * 4;
        int kk = k0 + r, oo = o0 + c;
        tl[r][c] = (kk < K && oo < O) ? src[(size_t)kk * O + oo] : 0.f;
    }
    __syncthreads();
    #pragma unroll
    for (int it = 0; it < 16; ++it) {
        int r = rr + it * 4;
        float v = tl[c][r];
        __bf16 hi = (__bf16)v;
        float lo = v - (float)hi;
        size_t pos = (size_t)(o0 + r) * Kpad + k0 + c;
        dst[pos] = hi;
        dst[LOFF + pos] = (__bf16)lo;
    }
}

// ---------------------------------------------------------------------------
// conv1 -> conv2 -> conv3 -> avgpool -> conv4 fused (round-7, frozen).
// ---------------------------------------------------------------------------
__global__ __launch_bounds__(512, 2) void conv1234_fused(
    const float* __restrict__ x, const __bf16* __restrict__ wT1,
    const float* __restrict__ b1,
    const float* __restrict__ bn1g, const float* __restrict__ bn1b,
    const float* __restrict__ bn1m, const float* __restrict__ bn1v,
    const __bf16* __restrict__ wT2, const float* __restrict__ b2,
    const float* __restrict__ bn2g, const float* __restrict__ bn2b,
    const float* __restrict__ bn2m, const float* __restrict__ bn2v,
    const __bf16* __restrict__ wT3, const float* __restrict__ b3,
    const __bf16* __restrict__ wT4, const float* __restrict__ b4,
    __bf16* __restrict__ h4)
{
    constexpr int LIN = 400, PAD = 1;
    constexpr int ROWS = 201;
    __shared__ __align__(16) __bf16 smem[2 * ROWS * 72];
    __shared__ __align__(16) __bf16 sw[2 * 64 * 72];

    __bf16* sx   = smem;
    __bf16* bufA = smem;
    __bf16* bufB = smem + 2 * 96 * 72;

    const int tid = threadIdx.x;
    const int n = blockIdx.x;
    const int wave = tid >> 6, lane = tid & 63;
    const int m = lane & 15, quad = lane >> 4;

    // phase 0: x-stage
    {
        const float* xg = x + (size_t)n * 64 * LIN;
        if (tid < 128) {
            int v = (tid >> 6) ? 401 : 0;
            sx[((v & 1) * ROWS + (v >> 1)) * 72 + (tid & 63)] = (__bf16)0.f;
        }
        constexpr int ITEMS = 16 * (LIN / 4);
        #pragma unroll
        for (int it = 0; it < 4; ++it) {
            int idx = it * 512 + tid;
            if (idx < ITEMS) {
                int jj = idx & 3;
                int g  = (idx >> 2) & 15;
                int q  = (idx >> 6) * 4 + jj;
                const float* xp = xg + (size_t)(4 * g) * LIN + 4 * q;
                float fa[4][4];
                #pragma unroll
                for (int u = 0; u < 4; ++u)
                    *(float4*)&fa[u][0] = *(const float4*)(xp + (size_t)u * LIN);
                #pragma unroll
                for (int e = 0; e < 4; ++e) {
                    int v = 4 * q + e + PAD;
                    bf16x4 wv = { (__bf16)fa[0][e], (__bf16)fa[1][e],
                                  (__bf16)fa[2][e], (__bf16)fa[3][e] };
                    *(bf16x4*)&sx[((v & 1) * ROWS + (v >> 1)) * 72 + 4 * g] = wv;
                }
            }
        }
    }

    // phase 1: conv1
    const int tile = wave >> 1;
    const int coh  = (wave & 1) * 32;
    {
        f32x4 acc[3][2];
        #pragma unroll
        for (int mi = 0; mi < 3; ++mi)
            #pragma unroll
            for (int nj = 0; nj < 2; ++nj)
                acc[mi][nj] = (f32x4){0.f, 0.f, 0.f, 0.f};

        for (int kb = 0; kb < 20; kb += 2) {
            if (kb) __syncthreads();
            #pragma unroll
            for (int i = 0; i < 2; ++i) {
                int idx = i * 512 + tid;
                int r = idx >> 3, p = idx & 7;
                *(uint4*)(sw + (size_t)r * 72 + p * 8) =
                    *(const uint4*)(wT1 + (size_t)(kb + (r >> 6)) * 4096 + (r & 63) * 64 + p * 8);
            }
            __syncthreads();

            #pragma unroll
            for (int kp2 = 0; kp2 < 2; ++kp2) {
                const int kp = kb + kp2;
                const int buf = kp & 1, rowoff = kp >> 1;
                const __bf16* abase = sx + ((size_t)buf * ROWS + tile * 48 + m + rowoff) * 72;
                const __bf16* bbase = sw + (size_t)(kp2 * 64 + coh + m) * 72;
                #pragma unroll
                for (int s = 0; s < 2; ++s) {
                    bf16x8 af[3], bfr[2];
                    #pragma unroll
                    for (int mi = 0; mi < 3; ++mi)
                        af[mi] = *(const bf16x8*)(abase + mi * (16 * 72) + s * 32 + quad * 8);
                    #pragma unroll
                    for (int nj = 0; nj < 2; ++nj)
                        bfr[nj] = *(const bf16x8*)(bbase + nj * (16 * 72) + s * 32 + quad * 8);
                    #pragma unroll
                    for (int mi = 0; mi < 3; ++mi)
                        #pragma unroll
                        for (int nj = 0; nj < 2; ++nj)
                            acc[mi][nj] = __builtin_amdgcn_mfma_f32_16x16x32_bf16(
                                af[mi], bfr[nj], acc[mi][nj], 0, 0, 0);
                }
            }
        }
        __syncthreads();

        #pragma unroll
        for (int nj = 0; nj < 2; ++nj) {
            const int co = coh + nj * 16 + m;
            const float bi = b1[co];
            const float inv   = bn1g[co] / sqrtf(bn1v[co] + 1e-5f);
            const float shift = bn1b[co] - bn1m[co] * inv;
            #pragma unroll
            for (int mi = 0; mi < 3; ++mi)
                #pragma unroll
                for (int r = 0; r < 4; ++r) {
                    int t = tile * 48 + mi * 16 + quad * 4 + r;
                    float v = elu_f(acc[mi][nj][r] + bi) * inv + shift;
                    bufA[((size_t)(t & 1) * 96 + (t >> 1)) * 72 + co] = (__bf16)v;
                }
        }
    }
    __syncthreads();

    // phase 2: conv2
    const int th  = wave >> 2;
    const int coq = wave & 3;
    {
        f32x4 acc[3];
        #pragma unroll
        for (int mi = 0; mi < 3; ++mi) acc[mi] = (f32x4){0.f, 0.f, 0.f, 0.f};

        for (int kb = 0; kb < 20; kb += 2) {
            __syncthreads();
            #pragma unroll
            for (int i = 0; i < 2; ++i) {
                int idx = i * 512 + tid;
                int r = idx >> 3, p = idx & 7;
                *(uint4*)(sw + (size_t)r * 72 + p * 8) =
                    *(const uint4*)(wT2 + (size_t)(kb + (r >> 6)) * 4096 + (r & 63) * 64 + p * 8);
            }
            __syncthreads();

            #pragma unroll
            for (int kp2 = 0; kp2 < 2; ++kp2) {
                const int kp = kb + kp2;
                const int buf = kp & 1, rowoff = kp >> 1;
                const int r0 = th * 48 + m + rowoff;
                const __bf16* bbase = sw + (size_t)(kp2 * 64 + coq * 16 + m) * 72;
                #pragma unroll
                for (int s = 0; s < 2; ++s) {
                    bf16x8 af[3], bfr;
                    #pragma unroll
                    for (int mi = 0; mi < 3; ++mi) {
                        int rr = r0 + mi * 16; if (rr > 95) rr = 95;
                        af[mi] = *(const bf16x8*)(bufA + ((size_t)buf * 96 + rr) * 72 + s * 32 + quad * 8);
                    }
                    bfr = *(const bf16x8*)(bbase + s * 32 + quad * 8);
                    #pragma unroll
                    for (int mi = 0; mi < 3; ++mi)
                        acc[mi] = __builtin_amdgcn_mfma_f32_16x16x32_bf16(
                            af[mi], bfr, acc[mi], 0, 0, 0);
                }
            }
        }

        const int co = coq * 16 + m;
        const float bi = b2[co];
        float inv = bn2g[co] / sqrtf(bn2v[co] + 1e-5f);
        float shift = bn2b[co] - bn2m[co] * inv;
        #pragma unroll
        for (int mi = 0; mi < 3; ++mi)
            #pragma unroll
            for (int r = 0; r < 4; ++r) {
                int t = th * 48 + mi * 16 + quad * 4 + r;
                if (t < 87) {
                    float v = elu_f(acc[mi][r] + bi) * inv + shift;
                    bufB[t * 72 + co] = (__bf16)v;
                }
            }
    }
    __syncthreads();

    // phase 3: conv3
    {
        const __bf16* wb = wT3 + (size_t)(coq * 16 + m) * 64 + quad * 8;
        bf16x8 bw[6][2];
        #pragma unroll
        for (int kp = 0; kp < 6; ++kp)
            #pragma unroll
            for (int s = 0; s < 2; ++s)
                bw[kp][s] = *(const bf16x8*)(wb + (size_t)kp * 4096 + s * 32);

        f32x4 acc[3];
        #pragma unroll
        for (int mi = 0; mi < 3; ++mi) acc[mi] = (f32x4){0.f, 0.f, 0.f, 0.f};

        #pragma unroll
        for (int kp = 0; kp < 6; ++kp) {
            const int r0 = th * 48 + m + kp;
            #pragma unroll
            for (int s = 0; s < 2; ++s) {
                bf16x8 af[3];
                #pragma unroll
                for (int mi = 0; mi < 3; ++mi) {
                    int rr = r0 + mi * 16; if (rr > 86) rr = 86;
                    af[mi] = *(const bf16x8*)(bufB + (size_t)rr * 72 + s * 32 + quad * 8);
                }
                #pragma unroll
                for (int mi = 0; mi < 3; ++mi)
                    acc[mi] = __builtin_amdgcn_mfma_f32_16x16x32_bf16(
                        af[mi], bw[kp][s], acc[mi], 0, 0, 0);
            }
        }

        const int co = coq * 16 + m;
        const float bi = b3[co];
        #pragma unroll
        for (int mi = 0; mi < 3; ++mi)
            #pragma unroll
            for (int r = 0; r < 4; ++r) {
                int t = th * 48 + mi * 16 + quad * 4 + r;
                if (t < 82)
                    bufA[(size_t)t * 72 + co] = (__bf16)elu_f(acc[mi][r] + bi);
            }
    }
    __syncthreads();

    // phase 4: avgpool
    #pragma unroll
    for (int it = 0; it < 5; ++it) {
        int idx = it * 512 + tid;
        int t = idx >> 6, co = idx & 63;
        float v = ((float)bufA[(2 * t) * 72 + co] + (float)bufA[(2 * t + 1) * 72 + co] +
                   (float)bufA[(2 * t + 2) * 72 + co]) * (1.f / 3.f);
        bufB[t * 72 + co] = (__bf16)v;
    }
    __syncthreads();

    // phase 5: conv4
    if (wave < 4) {
        const int co0 = wave * 16;
        const __bf16* wb = wT4 + (size_t)(co0 + m) * 64 + quad * 8;
        bf16x8 bw[6][2];
        #pragma unroll
        for (int kp = 0; kp < 6; ++kp)
            #pragma unroll
            for (int s = 0; s < 2; ++s)
                bw[kp][s] = *(const bf16x8*)(wb + (size_t)kp * 4096 + s * 32);

        f32x4 acc4[3];
        #pragma unroll
        for (int mi = 0; mi < 3; ++mi) acc4[mi] = (f32x4){0.f, 0.f, 0.f, 0.f};

        #pragma unroll
        for (int kp = 0; kp < 6; ++kp) {
            const int r0 = m + kp;
            #pragma unroll
            for (int s = 0; s < 2; ++s) {
                bf16x8 af[3];
                #pragma unroll
                for (int mi = 0; mi < 3; ++mi) {
                    int rr = r0 + mi * 16; if (rr > 39) rr = 39;
                    af[mi] = *(const bf16x8*)(bufB + (size_t)rr * 72 + s * 32 + quad * 8);
                }
                #pragma unroll
                for (int mi = 0; mi < 3; ++mi)
                    acc4[mi] = __builtin_amdgcn_mfma_f32_16x16x32_bf16(
                        af[mi], bw[kp][s], acc4[mi], 0, 0, 0);
            }
        }

        const int co = co0 + m;
        const float bi = b4[co];
        #pragma unroll
        for (int mi = 0; mi < 3; ++mi)
            #pragma unroll
            for (int r = 0; r < 4; ++r) {
                int t = mi * 16 + quad * 4 + r;
                if (t < 35)
                    h4[((size_t)n * 35 + t) * 64 + co] = (__bf16)elu_f(acc4[mi][r] + bi);
            }
    }
}

// ---------------------------------------------------------------------------
// Attention pooling, one WAVE per (b,c) pair; 4 pairs per 256-thread block.
// h4 staging via aligned 8B bf16x4 row loads (the block's 4 pairs are always
// 4 consecutive channels of one b; pair0 % 4 == 0 and a block never crosses
// a 64-channel boundary). Same values, same sh layout as round 9.
// ---------------------------------------------------------------------------
__global__ __launch_bounds__(256) void attn_pool_k(
    const __bf16* __restrict__ h, const float* __restrict__ W,
    const float* __restrict__ ab, const float* __restrict__ u,
    float* __restrict__ out)
{
    __shared__ float sW[35 * 256];
    __shared__ float sh[4][16 * 35 + 5];
    const int tid = threadIdx.x;
    const int pair0 = blockIdx.x * 4;
    const int b0 = pair0 >> 6, c0 = pair0 & 63;
    for (int i = tid; i < 35 * 256; i += 256) sW[i] = W[i];
    {
        const __bf16* src = h + ((size_t)b0 * 560) * 64 + c0;
        for (int i = tid; i < 560; i += 256) {
            bf16x4 v = *(const bf16x4*)(src + (size_t)i * 64);
            sh[0][i] = (float)v[0];
            sh[1][i] = (float)v[1];
            sh[2][i] = (float)v[2];
            sh[3][i] = (float)v[3];
        }
    }
    __syncthreads();

    const int wave = tid >> 6, lane = tid & 63;
    const int bc = pair0 + wave;
    const float* shw = sh[wave];

    float myu[4], myb[4];
    #pragma unroll
    for (int p = 0; p < 4; ++p) { myu[p] = u[lane + 64 * p]; myb[p] = ab[lane + 64 * p]; }

    float dot[16][4];
    #pragma unroll
    for (int s = 0; s < 16; ++s)
        #pragma unroll
        for (int p = 0; p < 4; ++p) dot[s][p] = myb[p];

    for (int t = 0; t < 35; ++t) {
        float w0 = sW[t * 256 + lane];
        float w1 = sW[t * 256 + lane + 64];
        float w2 = sW[t * 256 + lane + 128];
        float w3 = sW[t * 256 + lane + 192];
        #pragma unroll
        for (int s = 0; s < 16; ++s) {
            float hv = shw[s * 35 + t];
            dot[s][0] = fmaf(hv, w0, dot[s][0]);
            dot[s][1] = fmaf(hv, w1, dot[s][1]);
            dot[s][2] = fmaf(hv, w2, dot[s][2]);
            dot[s][3] = fmaf(hv, w3, dot[s][3]);
        }
    }

    float sc[16];
    #pragma unroll
    for (int s = 0; s < 16; ++s) {
        float v = tanhf(dot[s][0]) * myu[0] + tanhf(dot[s][1]) * myu[1]
                + tanhf(dot[s][2]) * myu[2] + tanhf(dot[s][3]) * myu[3];
        #pragma unroll
        for (int off = 1; off < 64; off <<= 1) v += __shfl_xor(v, off, 64);
        sc[s] = v;
    }

    float mx = sc[0];
    #pragma unroll
    for (int s = 1; s < 16; ++s) mx = fmaxf(mx, sc[s]);
    float e[16], sum = 0.f;
    #pragma unroll
    for (int s = 0; s < 16; ++s) { e[s] = expf(sc[s] - mx); sum += e[s]; }
    float inv = 1.f / sum;

    if (lane < 35) {
        float acc = 0.f;
        #pragma unroll
        for (int s = 0; s < 16; ++s) acc = fmaf(shw[s * 35 + lane], e[s] * inv, acc);
        out[(size_t)bc * 35 + lane] = elu_f(acc);
    }
}

// ---------------------------------------------------------------------------
// Fused GIN stack, split-bf16 (hi/lo). Round-9 form (16 waves), frozen.
// ---------------------------------------------------------------------------
#define APLANE (64 * 264)

__device__ __forceinline__ void gin_gemm_dev(
    const __bf16* As,
    const __bf16* __restrict__ Wg, int Kpad, int wlo, int Kout,
    const float* __restrict__ bias,
    int mode, __bf16* Ad, float* __restrict__ outg)
{
    const int lane = threadIdx.x & 63;
    const int wave = threadIdx.x >> 6;
    const int o0 = wave * 16;
    if (o0 >= ((Kout + 63) & ~63)) return;
    const int m = lane & 15, quad = lane >> 4;

    f32x4 acc[4];
    #pragma unroll
    for (int mi = 0; mi < 4; ++mi)
        acc[mi] = (f32x4){0.f, 0.f, 0.f, 0.f};

    for (int k0 = 0; k0 < Kpad; k0 += 32) {
        bf16x8 ah[4], al[4], bh, bl;
        #pragma unroll
        for (int mi = 0; mi < 4; ++mi) {
            const __bf16* ap = As + (size_t)(mi * 16 + m) * 264 + k0 + quad * 8;
            ah[mi] = *(const bf16x8*)ap;
            al[mi] = *(const bf16x8*)(ap + APLANE);
        }
        {
            const __bf16* wp = Wg + (size_t)(o0 + m) * Kpad + k0 + quad * 8;
            bh = *(const bf16x8*)wp;
            bl = *(const bf16x8*)(wp + wlo);
        }
        #pragma unroll
        for (int mi = 0; mi < 4; ++mi) {
            acc[mi] = __builtin_amdgcn_mfma_f32_16x16x32_bf16(al[mi], bh, acc[mi], 0, 0, 0);
            acc[mi] = __builtin_amdgcn_mfma_f32_16x16x32_bf16(ah[mi], bl, acc[mi], 0, 0, 0);
            acc[mi] = __builtin_amdgcn_mfma_f32_16x16x32_bf16(ah[mi], bh, acc[mi], 0, 0, 0);
        }
    }

    const int o = o0 + m;
    const bool ovalid = (o < Kout);
    const float bi = ovalid ? bias[o] : 0.f;
    float v[4][4];
    #pragma unroll
    for (int mi = 0; mi < 4; ++mi)
        #pragma unroll
        for (int r = 0; r < 4; ++r)
            v[mi][r] = acc[mi][r] + bi;
    if (mode == 2) {
        if (ovalid) {
            #pragma unroll
            for (int mi = 0; mi < 4; ++mi)
                #pragma unroll
                for (int r = 0; r < 4; ++r)
                    outg[(size_t)(mi * 16 + quad * 4 + r) * Kout + o] = v[mi][r];
        }
    } else {
        float s = 0.f;
        #pragma unroll
        for (int mi = 0; mi < 4; ++mi)
            #pragma unroll
            for (int r = 0; r < 4; ++r) {
                float rv = ovalid ? fmaxf(v[mi][r], 0.f) : 0.f;
                v[mi][r] = rv;
                s += rv;
            }
        if (mode == 1) {
            s += __shfl_xor(s, 16, 64);
            s += __shfl_xor(s, 32, 64);
        } else {
            s = 0.f;
        }
        #pragma unroll
        for (int mi = 0; mi < 4; ++mi)
            #pragma unroll
            for (int r = 0; r < 4; ++r) {
                float a = v[mi][r] + s;
                __bf16 hi = (__bf16)a;
                size_t pos = (size_t)(mi * 16 + quad * 4 + r) * 264 + o;
                Ad[pos] = hi;
                Ad[APLANE + pos] = (__bf16)(a - (float)hi);
            }
    }
}

__global__ __launch_bounds__(1024) void gin_fused(
    const float* __restrict__ ha,
    const __bf16* __restrict__ gW0a, const __bf16* __restrict__ gW0b,
    const __bf16* __restrict__ gW1a, const __bf16* __restrict__ gW1b,
    const __bf16* __restrict__ gW2a, const __bf16* __restrict__ gW2b,
    const float* __restrict__ b0a, const float* __restrict__ b0b,
    const float* __restrict__ b1a, const float* __restrict__ b1b,
    const float* __restrict__ b2a, const float* __restrict__ b2b,
    float* __restrict__ H3)
{
    const int b = blockIdx.x, tid = threadIdx.x;
    __shared__ __align__(16) __bf16 sA[2][2 * APLANE];
    __shared__ float sS[64];
    const float* hab = ha + (size_t)b * 2240;

    if (tid < 64) {
        float s = 0.f;
        if (tid < 35)
            for (int n = 0; n < 64; ++n) s += hab[n * 35 + tid];
        sS[tid] = s;
    }
    __syncthreads();
    for (int idx = tid; idx < 64 * 64; idx += 1024) {
        int n = idx >> 6, k = idx & 63;
        float a = (k < 35) ? hab[n * 35 + k] + sS[k] : 0.f;
        __bf16 hi = (__bf16)a;
        sA[0][n * 264 + k] = hi;
        sA[0][APLANE + n * 264 + k] = (__bf16)(a - (float)hi);
    }
    __syncthreads();

    gin_gemm_dev(sA[0], gW0a, 64,  16384, 256, b0a, 0, sA[1], nullptr); __syncthreads();
    gin_gemm_dev(sA[1], gW0b, 256, 65536, 256, b0b, 1, sA[0], nullptr); __syncthreads();
    gin_gemm_dev(sA[0], gW1a, 256, 65536, 256, b1a, 0, sA[1], nullptr); __syncthreads();
    gin_gemm_dev(sA[1], gW1b, 256, 65536, 256, b1b, 1, sA[0], nullptr); __syncthreads();
    gin_gemm_dev(sA[0], gW2a, 256, 16384, 35,  b2a, 0, sA[1], nullptr); __syncthreads();
    gin_gemm_dev(sA[1], gW2b, 64,  4096,  35,  b2b, 2, nullptr, H3 + (size_t)b * 2240);
}

// ---------------------------------------------------------------------------
// Merged classifier, one block per b (32 blocks, 256 threads). Layer 1 walks
// the 16 K-chunks serially in kc order with the exact a0..a3 split of the old
// two-kernel path -> bit-identical. Deletes one launch + s1p round-trip.
// ---------------------------------------------------------------------------
__global__ __launch_bounds__(256) void cls_all(
    const float* __restrict__ H3,
    const float* __restrict__ w1, const float* __restrict__ b1,
    const float* __restrict__ w2, const float* __restrict__ b2,
    const float* __restrict__ w3, const float* __restrict__ b3,
    const float* __restrict__ w4, const float* __restrict__ b4,
    float* __restrict__ out)
{
    const int b = blockIdx.x, tid = threadIdx.x;
    __shared__ float hL[2240];
    __shared__ float s1[256];
    __shared__ float part[4][64];
    __shared__ float s2[64];
    __shared__ float s3[16];

    for (int i = tid; i < 2240; i += 256)
        hL[i] = H3[(size_t)b * 2240 + i];
    __syncthreads();

    {
        float acc = b1[tid];
        for (int kc = 0; kc < 16; ++kc) {
            const int k0 = kc * 140;
            float a0 = 0.f, a1 = 0.f, a2 = 0.f, a3 = 0.f;
            const float* wr = w1 + (size_t)k0 * 256 + tid;
            #pragma unroll
            for (int k = 0; k < 140; k += 4) {
                a0 = fmaf(hL[k0 + k],     wr[(size_t)k * 256],       a0);
                a1 = fmaf(hL[k0 + k + 1], wr[(size_t)(k + 1) * 256], a1);
                a2 = fmaf(hL[k0 + k + 2], wr[(size_t)(k + 2) * 256], a2);
                a3 = fmaf(hL[k0 + k + 3], wr[(size_t)(k + 3) * 256], a3);
            }
            acc += a0 + a1 + a2 + a3;
        }
        s1[tid] = elu_f(acc);
    }
    __syncthreads();

    {
        int kg = tid >> 6, o = tid & 63;
        float acc = 0.f;
        for (int k = kg * 64; k < kg * 64 + 64; ++k)
            acc = fmaf(s1[k], w2[k * 64 + o], acc);
        part[kg][o] = acc;
    }
    __syncthreads();
    if (tid < 64) {
        float acc = part[0][tid] + part[1][tid] + part[2][tid] + part[3][tid] + b2[tid];
        s2[tid] = elu_f(acc);
    }
    __syncthreads();
    if (tid < 16) {
        float acc = b3[tid];
        for (int k = 0; k < 64; ++k) acc = fmaf(s2[k], w3[k * 16 + tid], acc);
        s3[tid] = elu_f(acc);
    }
    __syncthreads();
    if (tid < 2) {
        float acc = b4[tid];
        for (int k = 0; k < 16; ++k) acc = fmaf(s3[k], w4[k * 2 + tid], acc);
        out[b * 2 + tid] = acc;
    }
}

// ---------------------------------------------------------------------------
extern "C" void kernel_launch(void* const* d_in, const int* in_sizes, int n_in,
                              void* d_out, int out_size, void* d_ws, size_t ws_size,
                              hipStream_t stream)
{
    const float* x     = (const float*)d_in[0];
    const float* w1    = (const float*)d_in[1];
    const float* b1    = (const float*)d_in[2];
    const float* bn1_g = (const float*)d_in[3];
    const float* bn1_b = (const float*)d_in[4];
    const float* bn1_m = (const float*)d_in[5];
    const float* bn1_v = (const float*)d_in[6];
    const float* w2    = (const float*)d_in[7];
    const float* b2    = (const float*)d_in[8];
    const float* bn2_g = (const float*)d_in[9];
    const float* bn2_b = (const float*)d_in[10];
    const float* bn2_m = (const float*)d_in[11];
    const float* bn2_v = (const float*)d_in[12];
    const float* w3    = (const float*)d_in[13];
    const float* b3    = (const float*)d_in[14];
    const float* w4    = (const float*)d_in[15];
    const float* b4    = (const float*)d_in[16];
    const float* attn_w = (const float*)d_in[17];
    const float* attn_b = (const float*)d_in[18];
    const float* attn_u = (const float*)d_in[19];
    const float* g0_w1 = (const float*)d_in[20];
    const float* g0_b1 = (const float*)d_in[21];
    const float* g0_w2 = (const float*)d_in[22];
    const float* g0_b2 = (const float*)d_in[23];
    const float* g1_w1 = (const float*)d_in[24];
    const float* g1_b1 = (const float*)d_in[25];
    const float* g1_w2 = (const float*)d_in[26];
    const float* g1_b2 = (const float*)d_in[27];
    const float* g2_w1 = (const float*)d_in[28];
    const float* g2_b1 = (const float*)d_in[29];
    const float* g2_w2 = (const float*)d_in[30];
    const float* g2_b2 = (const float*)d_in[31];
    const float* c_w1  = (const float*)d_in[32];
    const float* c_b1  = (const float*)d_in[33];
    const float* c_w2  = (const float*)d_in[34];
    const float* c_b2  = (const float*)d_in[35];
    const float* c_w3  = (const float*)d_in[36];
    const float* c_b3  = (const float*)d_in[37];
    const float* c_w4  = (const float*)d_in[38];
    const float* c_b4  = (const float*)d_in[39];
    float* out = (float*)d_out;

    char* ws = (char*)d_ws;
    __bf16* wT1  = (__bf16*)(ws + 0);
    __bf16* wT2  = (__bf16*)(ws + 163840);
    __bf16* wT3  = (__bf16*)(ws + 327680);
    __bf16* wT4  = (__bf16*)(ws + 376832);
    __bf16* h4   = (__bf16*)(ws + 13008896);   // [512][35][64]
    float*  ha   = (float*)(ws + 15302656);    // [32][64][35]
    __bf16* gW0a = (__bf16*)(ws + 15589376);
    __bf16* gW0b = (__bf16*)(ws + 15654912);
    __bf16* gW1a = (__bf16*)(ws + 15917056);
    __bf16* gW1b = (__bf16*)(ws + 16179200);
    __bf16* gW2a = (__bf16*)(ws + 16441344);
    __bf16* gW2b = (__bf16*)(ws + 16506880);
    float*  H3   = (float*)(ws + 16523264);    // [32][2240]

    prep_all<<<dim3(889), dim3(256), 0, stream>>>(
        w1, w2, w3, w4, wT1, wT2, wT3, wT4,
        g0_w1, g0_w2, g1_w1, g1_w2, g2_w1, g2_w2,
        gW0a, gW0b, gW1a, gW1b, gW2a, gW2b);

    conv1234_fused<<<dim3(512), dim3(512), 0, stream>>>(
        x, wT1, b1, bn1_g, bn1_b, bn1_m, bn1_v,
        wT2, b2, bn2_g, bn2_b, bn2_m, bn2_v,
        wT3, b3, wT4, b4, h4);

    attn_pool_k<<<dim3(512), dim3(256), 0, stream>>>(h4, attn_w, attn_b, attn_u, ha);

    gin_fused<<<dim3(32), dim3(1024), 0, stream>>>(
        ha, gW0a, gW0b, gW1a, gW1b, gW2a, gW2b,
        g0_b1, g0_b2, g1_b1, g1_b2, g2_b1, g2_b2, H3);

    cls_all<<<dim3(32), dim3(256), 0, stream>>>(
        H3, c_w1, c_b1, c_w2, c_b2, c_w3, c_b3, c_w4, c_b4, out);
}

// Round 13
// 275.552 us; speedup vs baseline: 1.1962x; 1.1962x over previous
//
#include <hip/hip_runtime.h>
#include <math.h>

typedef __attribute__((ext_vector_type(8))) __bf16 bf16x8;
typedef __attribute__((ext_vector_type(4))) __bf16 bf16x4;
typedef __attribute__((ext_vector_type(4))) float f32x4;

__device__ __forceinline__ float elu_f(float v) {
    return v > 0.f ? v : (expf(v) - 1.f);
}

// ---------------------------------------------------------------------------
// Merged prep: conv-weight reorder (blocks 0..831) + GIN transpose/hi-lo
// split (blocks 832..888).
// ---------------------------------------------------------------------------
__global__ __launch_bounds__(256) void prep_all(
    const float* __restrict__ w1, const float* __restrict__ w2,
    const float* __restrict__ w3, const float* __restrict__ w4,
    __bf16* __restrict__ t1, __bf16* __restrict__ t2,
    __bf16* __restrict__ t3, __bf16* __restrict__ t4,
    const float* __restrict__ g0w1, const float* __restrict__ g0w2,
    const float* __restrict__ g1w1, const float* __restrict__ g1w2,
    const float* __restrict__ g2w1, const float* __restrict__ g2w2,
    __bf16* __restrict__ d0, __bf16* __restrict__ d1, __bf16* __restrict__ d2,
    __bf16* __restrict__ d3, __bf16* __restrict__ d4, __bf16* __restrict__ d5)
{
    __shared__ float tl[64][68];
    const int bigbid = blockIdx.x;
    if (bigbid < 832) {
        int idx = bigbid * 256 + threadIdx.x;
        if (idx < 81920) {
            int k = idx / 4096, r = idx - k * 4096, co = r >> 6, ci = r & 63;
            t1[idx] = (__bf16)w1[(co * 64 + ci) * 20 + k];
        } else if (idx < 163840) {
            int j = idx - 81920;
            int k = j / 4096, r = j - k * 4096, co = r >> 6, ci = r & 63;
            t2[j] = (__bf16)w2[(co * 64 + ci) * 20 + k];
        } else if (idx < 188416) {
            int j = idx - 163840;
            int k = j / 4096, r = j - k * 4096, co = r >> 6, ci = r & 63;
            t3[j] = (__bf16)w3[(co * 64 + ci) * 6 + k];
        } else if (idx < 212992) {
            int j = idx - 188416;
            int k = j / 4096, r = j - k * 4096, co = r >> 6, ci = r & 63;
            t4[j] = (__bf16)w4[(co * 64 + ci) * 6 + k];
        }
        return;
    }
    int bid = bigbid - 832;
    const float* src; __bf16* dst; int K, O, Kpad, Opad, tile;
    if (bid < 4)       { src = g0w1; dst = d0; K = 35;   O = 256; Kpad = 64;   Opad = 256; tile = bid; }
    else if (bid < 20) { src = g0w2; dst = d1; K = 256;  O = 256; Kpad = 256;  Opad = 256; tile = bid - 4; }
    else if (bid < 36) { src = g1w1; dst = d2; K = 256;  O = 256; Kpad = 256;  Opad = 256; tile = bid - 20; }
    else if (bid < 52) { src = g1w2; dst = d3; K = 256;  O = 256; Kpad = 256;  Opad = 256; tile = bid - 36; }
    else if (bid < 56) { src = g2w1; dst = d4; K = 256;  O = 35;  Kpad = 256;  Opad = 64;  tile = bid - 52; }
    else               { src = g2w2; dst = d5; K = 35;   O = 35;  Kpad = 64;   Opad = 64;  tile = 0; }
    int ktiles = Kpad >> 6;
    int ot = tile / ktiles, kt = tile - ot * ktiles;
    int k0 = kt * 64, o0 = ot * 64;
    size_t LOFF = (size_t)Opad * Kpad;
    int c = threadIdx.x & 63, rr = threadIdx.x >> 6;
    #pragma unroll
    for (int it = 0; it < 16; ++it) {
        int r = rr + it * 4;
        int kk = k0 + r, oo = o0 + c;
        tl[r][c] = (kk < K && oo < O) ? src[(size_t)kk * O + oo] : 0.f;
    }
    __syncthreads();
    #pragma unroll
    for (int it = 0; it < 16; ++it) {
        int r = rr + it * 4;
        float v = tl[c][r];
        __bf16 hi = (__bf16)v;
        float lo = v - (float)hi;
        size_t pos = (size_t)(o0 + r) * Kpad + k0 + c;
        dst[pos] = hi;
        dst[LOFF + pos] = (__bf16)lo;
    }
}

// ---------------------------------------------------------------------------
// conv1 -> conv2 -> conv3 -> avgpool -> conv4 fused (round-7, frozen).
// ---------------------------------------------------------------------------
__global__ __launch_bounds__(512, 2) void conv1234_fused(
    const float* __restrict__ x, const __bf16* __restrict__ wT1,
    const float* __restrict__ b1,
    const float* __restrict__ bn1g, const float* __restrict__ bn1b,
    const float* __restrict__ bn1m, const float* __restrict__ bn1v,
    const __bf16* __restrict__ wT2, const float* __restrict__ b2,
    const float* __restrict__ bn2g, const float* __restrict__ bn2b,
    const float* __restrict__ bn2m, const float* __restrict__ bn2v,
    const __bf16* __restrict__ wT3, const float* __restrict__ b3,
    const __bf16* __restrict__ wT4, const float* __restrict__ b4,
    __bf16* __restrict__ h4)
{
    constexpr int LIN = 400, PAD = 1;
    constexpr int ROWS = 201;
    __shared__ __align__(16) __bf16 smem[2 * ROWS * 72];
    __shared__ __align__(16) __bf16 sw[2 * 64 * 72];

    __bf16* sx   = smem;
    __bf16* bufA = smem;
    __bf16* bufB = smem + 2 * 96 * 72;

    const int tid = threadIdx.x;
    const int n = blockIdx.x;
    const int wave = tid >> 6, lane = tid & 63;
    const int m = lane & 15, quad = lane >> 4;

    // phase 0: x-stage
    {
        const float* xg = x + (size_t)n * 64 * LIN;
        if (tid < 128) {
            int v = (tid >> 6) ? 401 : 0;
            sx[((v & 1) * ROWS + (v >> 1)) * 72 + (tid & 63)] = (__bf16)0.f;
        }
        constexpr int ITEMS = 16 * (LIN / 4);
        #pragma unroll
        for (int it = 0; it < 4; ++it) {
            int idx = it * 512 + tid;
            if (idx < ITEMS) {
                int jj = idx & 3;
                int g  = (idx >> 2) & 15;
                int q  = (idx >> 6) * 4 + jj;
                const float* xp = xg + (size_t)(4 * g) * LIN + 4 * q;
                float fa[4][4];
                #pragma unroll
                for (int u = 0; u < 4; ++u)
                    *(float4*)&fa[u][0] = *(const float4*)(xp + (size_t)u * LIN);
                #pragma unroll
                for (int e = 0; e < 4; ++e) {
                    int v = 4 * q + e + PAD;
                    bf16x4 wv = { (__bf16)fa[0][e], (__bf16)fa[1][e],
                                  (__bf16)fa[2][e], (__bf16)fa[3][e] };
                    *(bf16x4*)&sx[((v & 1) * ROWS + (v >> 1)) * 72 + 4 * g] = wv;
                }
            }
        }
    }

    // phase 1: conv1
    const int tile = wave >> 1;
    const int coh  = (wave & 1) * 32;
    {
        f32x4 acc[3][2];
        #pragma unroll
        for (int mi = 0; mi < 3; ++mi)
            #pragma unroll
            for (int nj = 0; nj < 2; ++nj)
                acc[mi][nj] = (f32x4){0.f, 0.f, 0.f, 0.f};

        for (int kb = 0; kb < 20; kb += 2) {
            if (kb) __syncthreads();
            #pragma unroll
            for (int i = 0; i < 2; ++i) {
                int idx = i * 512 + tid;
                int r = idx >> 3, p = idx & 7;
                *(uint4*)(sw + (size_t)r * 72 + p * 8) =
                    *(const uint4*)(wT1 + (size_t)(kb + (r >> 6)) * 4096 + (r & 63) * 64 + p * 8);
            }
            __syncthreads();

            #pragma unroll
            for (int kp2 = 0; kp2 < 2; ++kp2) {
                const int kp = kb + kp2;
                const int buf = kp & 1, rowoff = kp >> 1;
                const __bf16* abase = sx + ((size_t)buf * ROWS + tile * 48 + m + rowoff) * 72;
                const __bf16* bbase = sw + (size_t)(kp2 * 64 + coh + m) * 72;
                #pragma unroll
                for (int s = 0; s < 2; ++s) {
                    bf16x8 af[3], bfr[2];
                    #pragma unroll
                    for (int mi = 0; mi < 3; ++mi)
                        af[mi] = *(const bf16x8*)(abase + mi * (16 * 72) + s * 32 + quad * 8);
                    #pragma unroll
                    for (int nj = 0; nj < 2; ++nj)
                        bfr[nj] = *(const bf16x8*)(bbase + nj * (16 * 72) + s * 32 + quad * 8);
                    #pragma unroll
                    for (int mi = 0; mi < 3; ++mi)
                        #pragma unroll
                        for (int nj = 0; nj < 2; ++nj)
                            acc[mi][nj] = __builtin_amdgcn_mfma_f32_16x16x32_bf16(
                                af[mi], bfr[nj], acc[mi][nj], 0, 0, 0);
                }
            }
        }
        __syncthreads();

        #pragma unroll
        for (int nj = 0; nj < 2; ++nj) {
            const int co = coh + nj * 16 + m;
            const float bi = b1[co];
            const float inv   = bn1g[co] / sqrtf(bn1v[co] + 1e-5f);
            const float shift = bn1b[co] - bn1m[co] * inv;
            #pragma unroll
            for (int mi = 0; mi < 3; ++mi)
                #pragma unroll
                for (int r = 0; r < 4; ++r) {
                    int t = tile * 48 + mi * 16 + quad * 4 + r;
                    float v = elu_f(acc[mi][nj][r] + bi) * inv + shift;
                    bufA[((size_t)(t & 1) * 96 + (t >> 1)) * 72 + co] = (__bf16)v;
                }
        }
    }
    __syncthreads();

    // phase 2: conv2
    const int th  = wave >> 2;
    const int coq = wave & 3;
    {
        f32x4 acc[3];
        #pragma unroll
        for (int mi = 0; mi < 3; ++mi) acc[mi] = (f32x4){0.f, 0.f, 0.f, 0.f};

        for (int kb = 0; kb < 20; kb += 2) {
            __syncthreads();
            #pragma unroll
            for (int i = 0; i < 2; ++i) {
                int idx = i * 512 + tid;
                int r = idx >> 3, p = idx & 7;
                *(uint4*)(sw + (size_t)r * 72 + p * 8) =
                    *(const uint4*)(wT2 + (size_t)(kb + (r >> 6)) * 4096 + (r & 63) * 64 + p * 8);
            }
            __syncthreads();

            #pragma unroll
            for (int kp2 = 0; kp2 < 2; ++kp2) {
                const int kp = kb + kp2;
                const int buf = kp & 1, rowoff = kp >> 1;
                const int r0 = th * 48 + m + rowoff;
                const __bf16* bbase = sw + (size_t)(kp2 * 64 + coq * 16 + m) * 72;
                #pragma unroll
                for (int s = 0; s < 2; ++s) {
                    bf16x8 af[3], bfr;
                    #pragma unroll
                    for (int mi = 0; mi < 3; ++mi) {
                        int rr = r0 + mi * 16; if (rr > 95) rr = 95;
                        af[mi] = *(const bf16x8*)(bufA + ((size_t)buf * 96 + rr) * 72 + s * 32 + quad * 8);
                    }
                    bfr = *(const bf16x8*)(bbase + s * 32 + quad * 8);
                    #pragma unroll
                    for (int mi = 0; mi < 3; ++mi)
                        acc[mi] = __builtin_amdgcn_mfma_f32_16x16x32_bf16(
                            af[mi], bfr, acc[mi], 0, 0, 0);
                }
            }
        }

        const int co = coq * 16 + m;
        const float bi = b2[co];
        float inv = bn2g[co] / sqrtf(bn2v[co] + 1e-5f);
        float shift = bn2b[co] - bn2m[co] * inv;
        #pragma unroll
        for (int mi = 0; mi < 3; ++mi)
            #pragma unroll
            for (int r = 0; r < 4; ++r) {
                int t = th * 48 + mi * 16 + quad * 4 + r;
                if (t < 87) {
                    float v = elu_f(acc[mi][r] + bi) * inv + shift;
                    bufB[t * 72 + co] = (__bf16)v;
                }
            }
    }
    __syncthreads();

    // phase 3: conv3
    {
        const __bf16* wb = wT3 + (size_t)(coq * 16 + m) * 64 + quad * 8;
        bf16x8 bw[6][2];
        #pragma unroll
        for (int kp = 0; kp < 6; ++kp)
            #pragma unroll
            for (int s = 0; s < 2; ++s)
                bw[kp][s] = *(const bf16x8*)(wb + (size_t)kp * 4096 + s * 32);

        f32x4 acc[3];
        #pragma unroll
        for (int mi = 0; mi < 3; ++mi) acc[mi] = (f32x4){0.f, 0.f, 0.f, 0.f};

        #pragma unroll
        for (int kp = 0; kp < 6; ++kp) {
            const int r0 = th * 48 + m + kp;
            #pragma unroll
            for (int s = 0; s < 2; ++s) {
                bf16x8 af[3];
                #pragma unroll
                for (int mi = 0; mi < 3; ++mi) {
                    int rr = r0 + mi * 16; if (rr > 86) rr = 86;
                    af[mi] = *(const bf16x8*)(bufB + (size_t)rr * 72 + s * 32 + quad * 8);
                }
                #pragma unroll
                for (int mi = 0; mi < 3; ++mi)
                    acc[mi] = __builtin_amdgcn_mfma_f32_16x16x32_bf16(
                        af[mi], bw[kp][s], acc[mi], 0, 0, 0);
            }
        }

        const int co = coq * 16 + m;
        const float bi = b3[co];
        #pragma unroll
        for (int mi = 0; mi < 3; ++mi)
            #pragma unroll
            for (int r = 0; r < 4; ++r) {
                int t = th * 48 + mi * 16 + quad * 4 + r;
                if (t < 82)
                    bufA[(size_t)t * 72 + co] = (__bf16)elu_f(acc[mi][r] + bi);
            }
    }
    __syncthreads();

    // phase 4: avgpool
    #pragma unroll
    for (int it = 0; it < 5; ++it) {
        int idx = it * 512 + tid;
        int t = idx >> 6, co = idx & 63;
        float v = ((float)bufA[(2 * t) * 72 + co] + (float)bufA[(2 * t + 1) * 72 + co] +
                   (float)bufA[(2 * t + 2) * 72 + co]) * (1.f / 3.f);
        bufB[t * 72 + co] = (__bf16)v;
    }
    __syncthreads();

    // phase 5: conv4
    if (wave < 4) {
        const int co0 = wave * 16;
        const __bf16* wb = wT4 + (size_t)(co0 + m) * 64 + quad * 8;
        bf16x8 bw[6][2];
        #pragma unroll
        for (int kp = 0; kp < 6; ++kp)
            #pragma unroll
            for (int s = 0; s < 2; ++s)
                bw[kp][s] = *(const bf16x8*)(wb + (size_t)kp * 4096 + s * 32);

        f32x4 acc4[3];
        #pragma unroll
        for (int mi = 0; mi < 3; ++mi) acc4[mi] = (f32x4){0.f, 0.f, 0.f, 0.f};

        #pragma unroll
        for (int kp = 0; kp < 6; ++kp) {
            const int r0 = m + kp;
            #pragma unroll
            for (int s = 0; s < 2; ++s) {
                bf16x8 af[3];
                #pragma unroll
                for (int mi = 0; mi < 3; ++mi) {
                    int rr = r0 + mi * 16; if (rr > 39) rr = 39;
                    af[mi] = *(const bf16x8*)(bufB + (size_t)rr * 72 + s * 32 + quad * 8);
                }
                #pragma unroll
                for (int mi = 0; mi < 3; ++mi)
                    acc4[mi] = __builtin_amdgcn_mfma_f32_16x16x32_bf16(
                        af[mi], bw[kp][s], acc4[mi], 0, 0, 0);
            }
        }

        const int co = co0 + m;
        const float bi = b4[co];
        #pragma unroll
        for (int mi = 0; mi < 3; ++mi)
            #pragma unroll
            for (int r = 0; r < 4; ++r) {
                int t = mi * 16 + quad * 4 + r;
                if (t < 35)
                    h4[((size_t)n * 35 + t) * 64 + co] = (__bf16)elu_f(acc4[mi][r] + bi);
            }
    }
}

// ---------------------------------------------------------------------------
// Attention pooling, one WAVE per (b,c) pair; 4 pairs per 256-thread block.
// h4 staging via aligned 8B bf16x4 row loads (kept from round 10/12: the
// block's 4 pairs are always 4 consecutive channels of one b).
// ---------------------------------------------------------------------------
__global__ __launch_bounds__(256) void attn_pool_k(
    const __bf16* __restrict__ h, const float* __restrict__ W,
    const float* __restrict__ ab, const float* __restrict__ u,
    float* __restrict__ out)
{
    __shared__ float sW[35 * 256];
    __shared__ float sh[4][16 * 35 + 5];
    const int tid = threadIdx.x;
    const int pair0 = blockIdx.x * 4;
    const int b0 = pair0 >> 6, c0 = pair0 & 63;
    for (int i = tid; i < 35 * 256; i += 256) sW[i] = W[i];
    {
        const __bf16* src = h + ((size_t)b0 * 560) * 64 + c0;
        for (int i = tid; i < 560; i += 256) {
            bf16x4 v = *(const bf16x4*)(src + (size_t)i * 64);
            sh[0][i] = (float)v[0];
            sh[1][i] = (float)v[1];
            sh[2][i] = (float)v[2];
            sh[3][i] = (float)v[3];
        }
    }
    __syncthreads();

    const int wave = tid >> 6, lane = tid & 63;
    const int bc = pair0 + wave;
    const float* shw = sh[wave];

    float myu[4], myb[4];
    #pragma unroll
    for (int p = 0; p < 4; ++p) { myu[p] = u[lane + 64 * p]; myb[p] = ab[lane + 64 * p]; }

    float dot[16][4];
    #pragma unroll
    for (int s = 0; s < 16; ++s)
        #pragma unroll
        for (int p = 0; p < 4; ++p) dot[s][p] = myb[p];

    for (int t = 0; t < 35; ++t) {
        float w0 = sW[t * 256 + lane];
        float w1 = sW[t * 256 + lane + 64];
        float w2 = sW[t * 256 + lane + 128];
        float w3 = sW[t * 256 + lane + 192];
        #pragma unroll
        for (int s = 0; s < 16; ++s) {
            float hv = shw[s * 35 + t];
            dot[s][0] = fmaf(hv, w0, dot[s][0]);
            dot[s][1] = fmaf(hv, w1, dot[s][1]);
            dot[s][2] = fmaf(hv, w2, dot[s][2]);
            dot[s][3] = fmaf(hv, w3, dot[s][3]);
        }
    }

    float sc[16];
    #pragma unroll
    for (int s = 0; s < 16; ++s) {
        float v = tanhf(dot[s][0]) * myu[0] + tanhf(dot[s][1]) * myu[1]
                + tanhf(dot[s][2]) * myu[2] + tanhf(dot[s][3]) * myu[3];
        #pragma unroll
        for (int off = 1; off < 64; off <<= 1) v += __shfl_xor(v, off, 64);
        sc[s] = v;
    }

    float mx = sc[0];
    #pragma unroll
    for (int s = 1; s < 16; ++s) mx = fmaxf(mx, sc[s]);
    float e[16], sum = 0.f;
    #pragma unroll
    for (int s = 0; s < 16; ++s) { e[s] = expf(sc[s] - mx); sum += e[s]; }
    float inv = 1.f / sum;

    if (lane < 35) {
        float acc = 0.f;
        #pragma unroll
        for (int s = 0; s < 16; ++s) acc = fmaf(shw[s * 35 + lane], e[s] * inv, acc);
        out[(size_t)bc * 35 + lane] = elu_f(acc);
    }
}

// ---------------------------------------------------------------------------
// Fused GIN stack, split-bf16 (hi/lo). Round-9 form (16 waves), frozen.
// ---------------------------------------------------------------------------
#define APLANE (64 * 264)

__device__ __forceinline__ void gin_gemm_dev(
    const __bf16* As,
    const __bf16* __restrict__ Wg, int Kpad, int wlo, int Kout,
    const float* __restrict__ bias,
    int mode, __bf16* Ad, float* __restrict__ outg)
{
    const int lane = threadIdx.x & 63;
    const int wave = threadIdx.x >> 6;
    const int o0 = wave * 16;
    if (o0 >= ((Kout + 63) & ~63)) return;
    const int m = lane & 15, quad = lane >> 4;

    f32x4 acc[4];
    #pragma unroll
    for (int mi = 0; mi < 4; ++mi)
        acc[mi] = (f32x4){0.f, 0.f, 0.f, 0.f};

    for (int k0 = 0; k0 < Kpad; k0 += 32) {
        bf16x8 ah[4], al[4], bh, bl;
        #pragma unroll
        for (int mi = 0; mi < 4; ++mi) {
            const __bf16* ap = As + (size_t)(mi * 16 + m) * 264 + k0 + quad * 8;
            ah[mi] = *(const bf16x8*)ap;
            al[mi] = *(const bf16x8*)(ap + APLANE);
        }
        {
            const __bf16* wp = Wg + (size_t)(o0 + m) * Kpad + k0 + quad * 8;
            bh = *(const bf16x8*)wp;
            bl = *(const bf16x8*)(wp + wlo);
        }
        #pragma unroll
        for (int mi = 0; mi < 4; ++mi) {
            acc[mi] = __builtin_amdgcn_mfma_f32_16x16x32_bf16(al[mi], bh, acc[mi], 0, 0, 0);
            acc[mi] = __builtin_amdgcn_mfma_f32_16x16x32_bf16(ah[mi], bl, acc[mi], 0, 0, 0);
            acc[mi] = __builtin_amdgcn_mfma_f32_16x16x32_bf16(ah[mi], bh, acc[mi], 0, 0, 0);
        }
    }

    const int o = o0 + m;
    const bool ovalid = (o < Kout);
    const float bi = ovalid ? bias[o] : 0.f;
    float v[4][4];
    #pragma unroll
    for (int mi = 0; mi < 4; ++mi)
        #pragma unroll
        for (int r = 0; r < 4; ++r)
            v[mi][r] = acc[mi][r] + bi;
    if (mode == 2) {
        if (ovalid) {
            #pragma unroll
            for (int mi = 0; mi < 4; ++mi)
                #pragma unroll
                for (int r = 0; r < 4; ++r)
                    outg[(size_t)(mi * 16 + quad * 4 + r) * Kout + o] = v[mi][r];
        }
    } else {
        float s = 0.f;
        #pragma unroll
        for (int mi = 0; mi < 4; ++mi)
            #pragma unroll
            for (int r = 0; r < 4; ++r) {
                float rv = ovalid ? fmaxf(v[mi][r], 0.f) : 0.f;
                v[mi][r] = rv;
                s += rv;
            }
        if (mode == 1) {
            s += __shfl_xor(s, 16, 64);
            s += __shfl_xor(s, 32, 64);
        } else {
            s = 0.f;
        }
        #pragma unroll
        for (int mi = 0; mi < 4; ++mi)
            #pragma unroll
            for (int r = 0; r < 4; ++r) {
                float a = v[mi][r] + s;
                __bf16 hi = (__bf16)a;
                size_t pos = (size_t)(mi * 16 + quad * 4 + r) * 264 + o;
                Ad[pos] = hi;
                Ad[APLANE + pos] = (__bf16)(a - (float)hi);
            }
    }
}

__global__ __launch_bounds__(1024) void gin_fused(
    const float* __restrict__ ha,
    const __bf16* __restrict__ gW0a, const __bf16* __restrict__ gW0b,
    const __bf16* __restrict__ gW1a, const __bf16* __restrict__ gW1b,
    const __bf16* __restrict__ gW2a, const __bf16* __restrict__ gW2b,
    const float* __restrict__ b0a, const float* __restrict__ b0b,
    const float* __restrict__ b1a, const float* __restrict__ b1b,
    const float* __restrict__ b2a, const float* __restrict__ b2b,
    float* __restrict__ H3)
{
    const int b = blockIdx.x, tid = threadIdx.x;
    __shared__ __align__(16) __bf16 sA[2][2 * APLANE];
    __shared__ float sS[64];
    const float* hab = ha + (size_t)b * 2240;

    if (tid < 64) {
        float s = 0.f;
        if (tid < 35)
            for (int n = 0; n < 64; ++n) s += hab[n * 35 + tid];
        sS[tid] = s;
    }
    __syncthreads();
    for (int idx = tid; idx < 64 * 64; idx += 1024) {
        int n = idx >> 6, k = idx & 63;
        float a = (k < 35) ? hab[n * 35 + k] + sS[k] : 0.f;
        __bf16 hi = (__bf16)a;
        sA[0][n * 264 + k] = hi;
        sA[0][APLANE + n * 264 + k] = (__bf16)(a - (float)hi);
    }
    __syncthreads();

    gin_gemm_dev(sA[0], gW0a, 64,  16384, 256, b0a, 0, sA[1], nullptr); __syncthreads();
    gin_gemm_dev(sA[1], gW0b, 256, 65536, 256, b0b, 1, sA[0], nullptr); __syncthreads();
    gin_gemm_dev(sA[0], gW1a, 256, 65536, 256, b1a, 0, sA[1], nullptr); __syncthreads();
    gin_gemm_dev(sA[1], gW1b, 256, 65536, 256, b1b, 1, sA[0], nullptr); __syncthreads();
    gin_gemm_dev(sA[0], gW2a, 256, 16384, 35,  b2a, 0, sA[1], nullptr); __syncthreads();
    gin_gemm_dev(sA[1], gW2b, 64,  4096,  35,  b2b, 2, nullptr, H3 + (size_t)b * 2240);
}

// ---------------------------------------------------------------------------
// Classifier layer 1, fp32, K-split: grid (b=32, kc=16). (round-9 form,
// restored after the round-12 cls_all regression: 512 parallel blocks hide
// the w1 load latency that a 32-block kc-serial loop cannot.)
// ---------------------------------------------------------------------------
__global__ __launch_bounds__(256) void cls1_part_k(
    const float* __restrict__ H3, const float* __restrict__ w1,
    float* __restrict__ s1p)
{
    const int b  = blockIdx.x;
    const int kc = blockIdx.y;
    const int k0 = kc * 140;
    __shared__ float sH[140];
    const int tid = threadIdx.x;
    if (tid < 140) sH[tid] = H3[(size_t)b * 2240 + k0 + tid];
    __syncthreads();
    const int o = (tid >> 6) * 64 + (tid & 63);
    float a0 = 0.f, a1 = 0.f, a2 = 0.f, a3 = 0.f;
    const float* wr = w1 + (size_t)k0 * 256 + o;
    #pragma unroll
    for (int k = 0; k < 140; k += 4) {
        a0 = fmaf(sH[k],     wr[(size_t)k * 256],       a0);
        a1 = fmaf(sH[k + 1], wr[(size_t)(k + 1) * 256], a1);
        a2 = fmaf(sH[k + 2], wr[(size_t)(k + 2) * 256], a2);
        a3 = fmaf(sH[k + 3], wr[(size_t)(k + 3) * 256], a3);
    }
    s1p[((size_t)kc * 32 + b) * 256 + o] = a0 + a1 + a2 + a3;
}

// ---------------------------------------------------------------------------
// Classifier: reduce K-split partials (+bias, ELU), then layers 2-4 (fp32).
// ---------------------------------------------------------------------------
__global__ __launch_bounds__(256) void cls234_k(
    const float* __restrict__ s1p, const float* __restrict__ b1,
    const float* __restrict__ w2, const float* __restrict__ b2,
    const float* __restrict__ w3, const float* __restrict__ b3,
    const float* __restrict__ w4, const float* __restrict__ b4,
    float* __restrict__ out)
{
    const int b = blockIdx.x, tid = threadIdx.x;
    __shared__ float s1[256];
    __shared__ float part[4][64];
    __shared__ float s2[64];
    __shared__ float s3[16];
    {
        float acc = b1[tid];
        #pragma unroll
        for (int kc = 0; kc < 16; ++kc)
            acc += s1p[((size_t)kc * 32 + b) * 256 + tid];
        s1[tid] = elu_f(acc);
    }
    __syncthreads();
    {
        int kg = tid >> 6, o = tid & 63;
        float acc = 0.f;
        for (int k = kg * 64; k < kg * 64 + 64; ++k)
            acc = fmaf(s1[k], w2[k * 64 + o], acc);
        part[kg][o] = acc;
    }
    __syncthreads();
    if (tid < 64) {
        float acc = part[0][tid] + part[1][tid] + part[2][tid] + part[3][tid] + b2[tid];
        s2[tid] = elu_f(acc);
    }
    __syncthreads();
    if (tid < 16) {
        float acc = b3[tid];
        for (int k = 0; k < 64; ++k) acc = fmaf(s2[k], w3[k * 16 + tid], acc);
        s3[tid] = elu_f(acc);
    }
    __syncthreads();
    if (tid < 2) {
        float acc = b4[tid];
        for (int k = 0; k < 16; ++k) acc = fmaf(s3[k], w4[k * 2 + tid], acc);
        out[b * 2 + tid] = acc;
    }
}

// ---------------------------------------------------------------------------
extern "C" void kernel_launch(void* const* d_in, const int* in_sizes, int n_in,
                              void* d_out, int out_size, void* d_ws, size_t ws_size,
                              hipStream_t stream)
{
    const float* x     = (const float*)d_in[0];
    const float* w1    = (const float*)d_in[1];
    const float* b1    = (const float*)d_in[2];
    const float* bn1_g = (const float*)d_in[3];
    const float* bn1_b = (const float*)d_in[4];
    const float* bn1_m = (const float*)d_in[5];
    const float* bn1_v = (const float*)d_in[6];
    const float* w2    = (const float*)d_in[7];
    const float* b2    = (const float*)d_in[8];
    const float* bn2_g = (const float*)d_in[9];
    const float* bn2_b = (const float*)d_in[10];
    const float* bn2_m = (const float*)d_in[11];
    const float* bn2_v = (const float*)d_in[12];
    const float* w3    = (const float*)d_in[13];
    const float* b3    = (const float*)d_in[14];
    const float* w4    = (const float*)d_in[15];
    const float* b4    = (const float*)d_in[16];
    const float* attn_w = (const float*)d_in[17];
    const float* attn_b = (const float*)d_in[18];
    const float* attn_u = (const float*)d_in[19];
    const float* g0_w1 = (const float*)d_in[20];
    const float* g0_b1 = (const float*)d_in[21];
    const float* g0_w2 = (const float*)d_in[22];
    const float* g0_b2 = (const float*)d_in[23];
    const float* g1_w1 = (const float*)d_in[24];
    const float* g1_b1 = (const float*)d_in[25];
    const float* g1_w2 = (const float*)d_in[26];
    const float* g1_b2 = (const float*)d_in[27];
    const float* g2_w1 = (const float*)d_in[28];
    const float* g2_b1 = (const float*)d_in[29];
    const float* g2_w2 = (const float*)d_in[30];
    const float* g2_b2 = (const float*)d_in[31];
    const float* c_w1  = (const float*)d_in[32];
    const float* c_b1  = (const float*)d_in[33];
    const float* c_w2  = (const float*)d_in[34];
    const float* c_b2  = (const float*)d_in[35];
    const float* c_w3  = (const float*)d_in[36];
    const float* c_b3  = (const float*)d_in[37];
    const float* c_w4  = (const float*)d_in[38];
    const float* c_b4  = (const float*)d_in[39];
    float* out = (float*)d_out;

    char* ws = (char*)d_ws;
    __bf16* wT1  = (__bf16*)(ws + 0);
    __bf16* wT2  = (__bf16*)(ws + 163840);
    __bf16* wT3  = (__bf16*)(ws + 327680);
    __bf16* wT4  = (__bf16*)(ws + 376832);
    __bf16* h4   = (__bf16*)(ws + 13008896);   // [512][35][64]
    float*  ha   = (float*)(ws + 15302656);    // [32][64][35]
    __bf16* gW0a = (__bf16*)(ws + 15589376);
    __bf16* gW0b = (__bf16*)(ws + 15654912);
    __bf16* gW1a = (__bf16*)(ws + 15917056);
    __bf16* gW1b = (__bf16*)(ws + 16179200);
    __bf16* gW2a = (__bf16*)(ws + 16441344);
    __bf16* gW2b = (__bf16*)(ws + 16506880);
    float*  H3   = (float*)(ws + 16523264);    // [32][2240]
    float*  s1p  = (float*)(ws + 16809984);    // [16][32][256]

    prep_all<<<dim3(889), dim3(256), 0, stream>>>(
        w1, w2, w3, w4, wT1, wT2, wT3, wT4,
        g0_w1, g0_w2, g1_w1, g1_w2, g2_w1, g2_w2,
        gW0a, gW0b, gW1a, gW1b, gW2a, gW2b);

    conv1234_fused<<<dim3(512), dim3(512), 0, stream>>>(
        x, wT1, b1, bn1_g, bn1_b, bn1_m, bn1_v,
        wT2, b2, bn2_g, bn2_b, bn2_m, bn2_v,
        wT3, b3, wT4, b4, h4);

    attn_pool_k<<<dim3(512), dim3(256), 0, stream>>>(h4, attn_w, attn_b, attn_u, ha);

    gin_fused<<<dim3(32), dim3(1024), 0, stream>>>(
        ha, gW0a, gW0b, gW1a, gW1b, gW2a, gW2b,
        g0_b1, g0_b2, g1_b1, g1_b2, g2_b1, g2_b2, H3);

    cls1_part_k<<<dim3(32, 16), dim3(256), 0, stream>>>(H3, c_w1, s1p);
    cls234_k<<<dim3(32), dim3(256), 0, stream>>>(s1p, c_b1, c_w2, c_b2, c_w3, c_b3,
                                                 c_w4, c_b4, out);
}